// Round 11
// baseline (140.306 us; speedup 1.0000x reference)
//
#include <hip/hip_runtime.h>

// Problem geometry
#define TOT   19267584   // 128*768*14*14 == 128*3*224*224
#define MROWS 25088      // 128*196 patches
#define KD    768        // 3*16*16
#define NPB   196
#define CHW   150528     // 768*196

typedef unsigned int uint;
typedef __attribute__((ext_vector_type(4))) int i32x4;

// workspace layout (bytes)
#define OFF_AQ   0ull              // i8 aq_t[196][12][128][64] = 19,267,584 ; aliased: k1[p][oc]
#define OFF_WQ   19267584ull       // i8 wq_t[6][12][128][64] = 589,824 ; aliased after gemm: pm2/px2
#define OFF_WSC  19857408ull       // float w_scale[768]
#define OFF_INV  19860480ull       // float inv[768]
#define OFF_SHF  19863552ull       // float shift[768]
#define OFF_PA   19866624ull       // float pA[1176]  (max|x| partials)
#define OFF_PB   19871328ull       // float pB[1176]  (max|y_conv| partials)
#define OFF_SC   19876032ull       // uint sc[4]: s1, s2, s3, ps bits
#define OFF_PMN  19886880ull       // float pmn[1568][768] = 4,816,896
#define OFF_PMX  24703776ull       // float pmx[1568][768] = 4,816,896
// pm2/px2 (16x768 floats each) overlay the dead wq region:
#define OFF_PM2  19267584ull
#define OFF_PX2  19316736ull

__device__ __forceinline__ float wave_max(float v) {
#pragma unroll
  for (int off = 32; off > 0; off >>= 1) v = fmaxf(v, __shfl_xor(v, off));
  return v;
}

// block max for 256-thread blocks (4 waves)
__device__ __forceinline__ float block_max(float v) {
  __shared__ float red[4];
  v = wave_max(v);
  __syncthreads();
  if ((threadIdx.x & 63) == 0) red[threadIdx.x >> 6] = v;
  __syncthreads();
  return fmaxf(fmaxf(red[0], red[1]), fmaxf(red[2], red[3]));
}

// tiled i8 address: [blk128][ks][row128][64]
__device__ __forceinline__ size_t tiled_addr(int row, int k) {
  return (size_t)(row >> 7) * 98304 + (size_t)(k >> 6) * 8192 + ((row & 127) << 6) + (k & 63);
}

// ---------------- K0: fused max|x| partials (blocks 0..1175) + weight quant (1176..1943) ----
__global__ void k_max_wq(const float* __restrict__ x, float* __restrict__ pA,
                         const float* __restrict__ W, const float* __restrict__ gamma,
                         const float* __restrict__ beta, const float* __restrict__ rmean,
                         const float* __restrict__ rvar, signed char* __restrict__ wq,
                         float* __restrict__ wscale, float* __restrict__ inv_,
                         float* __restrict__ shf) {
  if (blockIdx.x < 1176) {
    const int i0 = blockIdx.x * 256 + threadIdx.x;   // 1176*256*16 = TOT/4 exact
    const float4* x4 = (const float4*)x;
    float m = 0.f;
#pragma unroll
    for (int j = 0; j < 16; j += 4) {
      float4 a = x4[i0 + (j + 0) * 301056];
      float4 b = x4[i0 + (j + 1) * 301056];
      float4 c = x4[i0 + (j + 2) * 301056];
      float4 d = x4[i0 + (j + 3) * 301056];
      m = fmaxf(m, fmaxf(fmaxf(fabsf(a.x), fabsf(a.y)), fmaxf(fabsf(a.z), fabsf(a.w))));
      m = fmaxf(m, fmaxf(fmaxf(fabsf(b.x), fabsf(b.y)), fmaxf(fabsf(b.z), fabsf(b.w))));
      m = fmaxf(m, fmaxf(fmaxf(fabsf(c.x), fabsf(c.y)), fmaxf(fabsf(c.z), fabsf(c.w))));
      m = fmaxf(m, fmaxf(fmaxf(fabsf(d.x), fabsf(d.y)), fmaxf(fabsf(d.z), fabsf(d.w))));
    }
    float bm = block_max(m);
    if (threadIdx.x == 0) pA[blockIdx.x] = bm;
  } else {
    const int oc = blockIdx.x - 1176;
    const float* row = W + oc * KD;
    float m = 0.f;
    for (int k = threadIdx.x; k < KD; k += 256) m = fmaxf(m, fabsf(row[k]));
    const float ws_ = block_max(m) / 127.0f;
    for (int k = threadIdx.x; k < KD; k += 256)
      wq[tiled_addr(oc, k)] = (signed char)(int)rintf(row[k] / ws_);
    if (threadIdx.x == 0) {
      wscale[oc] = ws_;
      float iv = gamma[oc] / sqrtf(rvar[oc] + 1e-5f);
      inv_[oc] = iv;
      shf[oc] = __fsub_rn(beta[oc], __fmul_rn(rmean[oc], iv));  // jax: mul then sub, no fma
    }
  }
}

// ---------------- K1: im2col + quant -> TILED aq; folds s0-combine; publishes ps ------------
__global__ void k_im2col(const float* __restrict__ x, const float* __restrict__ pA,
                         signed char* __restrict__ aq, uint* __restrict__ sc) {
  float mm = 0.f;
  for (int i = threadIdx.x; i < 1176; i += 256) mm = fmaxf(mm, pA[i]);
  const float ps = block_max(mm) / 127.0f;
  if (blockIdx.x == 0 && threadIdx.x == 0) sc[3] = __float_as_uint(ps);
  const int u = blockIdx.x * 256 + threadIdx.x;   // u < 1,204,224 = 25088*48 exact
  const int p = u / 48, r = u - p * 48;           // patch, (c,kh) row; k0 = r*16
  const int c = r >> 4, kh = r & 15;
  const int b = p / NPB, pp = p - b * NPB;
  const int ph = pp / 14, pw = pp - ph * 14;
  const float* src = x + (((b * 3 + c) * 224 + ph * 16 + kh) * 224 + pw * 16);
  float4 v0 = *(const float4*)(src);
  float4 v1 = *(const float4*)(src + 4);
  float4 v2 = *(const float4*)(src + 8);
  float4 v3 = *(const float4*)(src + 12);
#define Q8(v) ((int)fminf(fmaxf(rintf((v) / ps), -127.f), 127.f) & 255)
  uint4 o;
  o.x = Q8(v0.x) | (Q8(v0.y) << 8) | (Q8(v0.z) << 16) | ((uint)Q8(v0.w) << 24);
  o.y = Q8(v1.x) | (Q8(v1.y) << 8) | (Q8(v1.z) << 16) | ((uint)Q8(v1.w) << 24);
  o.z = Q8(v2.x) | (Q8(v2.y) << 8) | (Q8(v2.z) << 16) | ((uint)Q8(v2.w) << 24);
  o.w = Q8(v3.x) | (Q8(v3.y) << 8) | (Q8(v3.z) << 16) | ((uint)Q8(v3.w) << 24);
#undef Q8
  // tiled dest: [p>>7][ks=r>>2][p&127][kcol=(r&3)*16]
  *(uint4*)(aq + (size_t)(p >> 7) * 98304 + (size_t)(r >> 2) * 8192 + ((p & 127) << 6) +
            ((r & 3) << 4)) = o;
}

// ---------------- K2: i8 MFMA GEMM — tiled contiguous staging + depth-2 counted vmcnt -------
__device__ __forceinline__ void gl_lds16(const void* g, void* l) {
  __builtin_amdgcn_global_load_lds((const __attribute__((address_space(1))) void*)g,
                                   (__attribute__((address_space(3))) void*)l, 16, 0, 0);
}

__global__ __launch_bounds__(256) void k_gemm(const signed char* __restrict__ aq,
                                              const signed char* __restrict__ wq,
                                              const float* __restrict__ bias,
                                              const float* __restrict__ wscale,
                                              const uint* __restrict__ sc,
                                              float* __restrict__ y,
                                              float* __restrict__ pB) {
  __shared__ __align__(16) signed char lA[3][8192];   // 128 rows x 64 K (i8), 3-deep
  __shared__ __align__(16) signed char lB[3][8192];
  const int tid = threadIdx.x, lane = tid & 63, wv = tid >> 6;
  // XCD-aware swizzle (1176 = 8*147, bijective) + bn-inner: 6 consecutive blocks share A-tile
  const int bsw = (blockIdx.x & 7) * 147 + (blockIdx.x >> 3);
  const int bm = bsw / 6, bn = bsw - 6 * (bsw / 6);
  const int wr = wv >> 1, wc = wv & 1;               // 2x2 waves, 64x64 each
  const float ps_ = __uint_as_float(sc[3]);          // published by im2col (already /127)

  // staging: tile chunk = 1KB contiguous; rule-21 swizzle pair (source XOR, LDS linear)
  const int ci0 = wv * 2, ci1 = wv * 2 + 1;
  const int lo = ((lane >> 2) << 6) + (((lane & 3) ^ ((lane >> 3) & 3)) << 4);
  const signed char* gA0 = aq + (size_t)bm * 98304 + ci0 * 1024 + lo;
  const signed char* gA1 = aq + (size_t)bm * 98304 + ci1 * 1024 + lo;
  const signed char* gB0 = wq + (size_t)bn * 98304 + ci0 * 1024 + lo;
  const signed char* gB1 = wq + (size_t)bn * 98304 + ci1 * 1024 + lo;

  i32x4 acc[4][4];
#pragma unroll
  for (int m = 0; m < 4; ++m)
#pragma unroll
    for (int n = 0; n < 4; ++n) acc[m][n] = (i32x4){0, 0, 0, 0};

  const int rbase = lane & 15;
  // read k-offset: wanted piece (lane>>4) XOR row-swizzle ((lane>>1)&3); 2-way conflicts
  const int kg = ((lane >> 4) << 4) ^ (((lane >> 1) & 3) << 4);

#define STAGE(T, B)                                   \
  {                                                   \
    const size_t kk_ = (size_t)(T) * 8192;            \
    gl_lds16(gA0 + kk_, &lA[B][ci0 * 1024]);          \
    gl_lds16(gA1 + kk_, &lA[B][ci1 * 1024]);          \
    gl_lds16(gB0 + kk_, &lB[B][ci0 * 1024]);          \
    gl_lds16(gB1 + kk_, &lB[B][ci1 * 1024]);          \
  }

  STAGE(0, 0)
  STAGE(1, 1)
#pragma unroll
  for (int t = 0; t < 12; ++t) {
    // counted wait: own 4 oldest (tile t) retired; tile t+1's 4 stay in flight
    if (t < 11) { asm volatile("s_waitcnt vmcnt(4)" ::: "memory"); }
    else        { asm volatile("s_waitcnt vmcnt(0)" ::: "memory"); }
    __builtin_amdgcn_s_barrier();          // all waves: tile t fully in LDS
    __builtin_amdgcn_sched_barrier(0);
    const int b = t % 3;
    i32x4 af[4], bfr[4];
#pragma unroll
    for (int m = 0; m < 4; ++m)
      af[m] = *(const i32x4*)&lA[b][(wr * 64 + m * 16 + rbase) * 64 + kg];
#pragma unroll
    for (int n = 0; n < 4; ++n)
      bfr[n] = *(const i32x4*)&lB[b][(wc * 64 + n * 16 + rbase) * 64 + kg];
    if (t < 10) STAGE(t + 2, (t + 2) % 3)  // depth-2 prefetch, disjoint from buf t%3
#pragma unroll
    for (int m = 0; m < 4; ++m)
#pragma unroll
      for (int n = 0; n < 4; ++n)
        acc[m][n] = __builtin_amdgcn_mfma_i32_16x16x64_i8(bfr[n], af[m], acc[m][n], 0, 0, 0);
  }
#undef STAGE

  // epilogue (operand-swapped C layout): lane holds 4 consecutive oc, p = lane&15; y is [p][oc]
  float lmax = 0.f;
#pragma unroll
  for (int n = 0; n < 4; ++n) {
    const int ocb = bn * 128 + wc * 64 + n * 16 + ((lane >> 4) << 2);
    const float4 ws4 = *(const float4*)&wscale[ocb];
    const float4 b4 = *(const float4*)&bias[ocb];
    const float c0 = ws4.x * ps_, c1 = ws4.y * ps_, c2 = ws4.z * ps_, c3 = ws4.w * ps_;
    const float i0 = rintf(b4.x / c0), i1 = rintf(b4.y / c1);
    const float i2 = rintf(b4.z / c2), i3 = rintf(b4.w / c3);
#pragma unroll
    for (int m = 0; m < 4; ++m) {
      const int p = bm * 128 + wr * 64 + m * 16 + rbase;
      float4 o;
      o.x = ((float)acc[m][n][0] + i0) * c0;
      o.y = ((float)acc[m][n][1] + i1) * c1;
      o.z = ((float)acc[m][n][2] + i2) * c2;
      o.w = ((float)acc[m][n][3] + i3) * c3;
      lmax = fmaxf(lmax, fmaxf(fmaxf(fabsf(o.x), fabsf(o.y)), fmaxf(fabsf(o.z), fabsf(o.w))));
      *(float4*)(y + (size_t)p * 768 + ocb) = o;
    }
  }
  float bm_ = block_max(lmax);
  if (tid == 0) pB[blockIdx.x] = bm_;
}

// ---------------- K3: gelu pass on [p][oc]: 192 thr, float4 loads, coalesced partials -------
__global__ void k_gelu(const float* __restrict__ y, const float* __restrict__ pB,
                       signed char* __restrict__ k1, float* __restrict__ pmn,
                       float* __restrict__ pmx) {
  const int b = blockIdx.x;            // 1568 blocks x 16 patch rows; 192 threads (3 waves)
  const int t = threadIdx.x;
  __shared__ float red[3];
  __shared__ float tab[255];
  float mm = 0.f;
  for (int i = t; i < 1176; i += 192) mm = fmaxf(mm, pB[i]);
  mm = wave_max(mm);
  __syncthreads();
  if ((t & 63) == 0) red[t >> 6] = mm;
  __syncthreads();
  const float s1 = fmaxf(fmaxf(red[0], red[1]), red[2]) / 127.0f;
  for (int i = t; i < 255; i += 192) {
    float y1 = (float)(i - 127) * s1;
    float e = erff(y1 * 0.70710678118654752f);
    tab[i] = (y1 * (e + 1.0f)) * 0.5f;
  }
  __syncthreads();
  // thread owns channels 4t..4t+3 across 16 rows
  float mn0 = 1e30f, mx0 = -1e30f, mn1 = 1e30f, mx1 = -1e30f;
  float mn2 = 1e30f, mx2 = -1e30f, mn3 = 1e30f, mx3 = -1e30f;
  const float4* y4 = (const float4*)y + (size_t)b * 16 * 192 + t;
  char4* k4 = (char4*)k1 + (size_t)b * 16 * 192 + t;
#pragma unroll 4
  for (int row = 0; row < 16; ++row) {
    float4 v = y4[row * 192];
    int a = (int)fminf(fmaxf(rintf(v.x / s1), -127.f), 127.f);
    int bq = (int)fminf(fmaxf(rintf(v.y / s1), -127.f), 127.f);
    int cq = (int)fminf(fmaxf(rintf(v.z / s1), -127.f), 127.f);
    int dq = (int)fminf(fmaxf(rintf(v.w / s1), -127.f), 127.f);
    char4 kk;
    kk.x = (signed char)a; kk.y = (signed char)bq;
    kk.z = (signed char)cq; kk.w = (signed char)dq;
    k4[row * 192] = kk;
    float g0 = tab[a + 127], g1 = tab[bq + 127], g2 = tab[cq + 127], g3 = tab[dq + 127];
    mn0 = fminf(mn0, g0); mx0 = fmaxf(mx0, g0);
    mn1 = fminf(mn1, g1); mx1 = fmaxf(mx1, g1);
    mn2 = fminf(mn2, g2); mx2 = fmaxf(mx2, g2);
    mn3 = fminf(mn3, g3); mx3 = fmaxf(mx3, g3);
  }
  float4 omn, omx;
  omn.x = mn0; omn.y = mn1; omn.z = mn2; omn.w = mn3;
  omx.x = mx0; omx.y = mx1; omx.z = mx2; omx.w = mx3;
  ((float4*)pmn)[(size_t)b * 192 + t] = omn;   // pmn[b][768] — coalesced
  ((float4*)pmx)[(size_t)b * 192 + t] = omx;
}

// ---------------- K4: stage-1 channel reduce: 192 blocks (12 cg x 16 row-chunks) ------------
__global__ void k_chred(const float* __restrict__ pmn, const float* __restrict__ pmx,
                        float* __restrict__ pm2, float* __restrict__ px2) {
  const int cg = blockIdx.x % 12, rc = blockIdx.x / 12;
  const int lane = threadIdx.x & 63, wv = threadIdx.x >> 6;
  const int c = cg * 64 + lane;
  float lo = 1e30f, hi = -1e30f;
  for (int i = wv; i < 98; i += 4) {
    const size_t a = (size_t)(rc * 98 + i) * 768 + c;   // 64 lanes = 256B coalesced
    lo = fminf(lo, pmn[a]);
    hi = fmaxf(hi, pmx[a]);
  }
  __shared__ float smn[4][64], smx[4][64];
  smn[wv][lane] = lo;
  smx[wv][lane] = hi;
  __syncthreads();
  if (threadIdx.x < 64) {
    float l = fminf(fminf(smn[0][lane], smn[1][lane]), fminf(smn[2][lane], smn[3][lane]));
    float h = fmaxf(fmaxf(smx[0][lane], smx[1][lane]), fmaxf(smx[2][lane], smx[3][lane]));
    pm2[rc * 768 + c] = l;
    px2[rc * 768 + c] = h;
  }
}

// ---------------- K5: scalars s1, s2, s3 (folds stage-2 channel reduce) --------------------
__global__ void k_scales(const float* __restrict__ pB, const float* __restrict__ pm2,
                         const float* __restrict__ px2, const float* __restrict__ inv_,
                         const float* __restrict__ shf, uint* __restrict__ sc) {
  const int t = threadIdx.x;
  float m = 0.f;
  for (int i = t; i < 1176; i += 256) m = fmaxf(m, pB[i]);
  const float s1 = block_max(m) / 127.0f;
  float cmn[3], cmx[3];
  float m2 = 0.f;
#pragma unroll
  for (int ci = 0; ci < 3; ++ci) {
    const int c = t + ci * 256;
    float mn = 1e30f, mx = -1e30f;
#pragma unroll
    for (int r = 0; r < 16; ++r) {
      mn = fminf(mn, pm2[r * 768 + c]);
      mx = fmaxf(mx, px2[r * 768 + c]);
    }
    cmn[ci] = mn;
    cmx[ci] = mx;
    m2 = fmaxf(m2, fmaxf(fabsf(mn), fabsf(mx)));
  }
  const float s2 = block_max(m2) / 127.0f;
  float m4 = 0.f;
#pragma unroll
  for (int ci = 0; ci < 3; ++ci) {
    const int c = t + ci * 256;
    float iv = inv_[c], sh = shf[c];
    float a = fminf(fmaxf(rintf(cmn[ci] / s2), -127.f), 127.f) * s2;
    float b = fminf(fmaxf(rintf(cmx[ci] / s2), -127.f), 127.f) * s2;
    float ya = __fadd_rn(__fmul_rn(a, iv), sh);
    float yb = __fadd_rn(__fmul_rn(b, iv), sh);
    m4 = fmaxf(m4, fmaxf(fabsf(ya), fabsf(yb)));
  }
  const float s3 = block_max(m4) / 127.0f;
  if (t == 0) {
    sc[0] = __float_as_uint(s1);
    sc[1] = __float_as_uint(s2);
    sc[2] = __float_as_uint(s3);
  }
}

// ---------------- K6: final via LDS transpose: coalesced k1 reads, 196B output runs --------
__global__ __launch_bounds__(256) void k_final(const signed char* __restrict__ k1,
                                               const uint* __restrict__ sc,
                                               const float* __restrict__ inv_,
                                               const float* __restrict__ shf,
                                               float* __restrict__ out) {
  __shared__ signed char ks[49 * 772];   // [q][772] padded (bank-spread for column reads)
  __shared__ float tab[255];
  const float s1 = __uint_as_float(sc[0]);
  const float s2 = __uint_as_float(sc[1]);
  const float s3 = __uint_as_float(sc[2]);
  const int t = threadIdx.x;
  for (int i = t; i < 255; i += 256) {
    float y1 = (float)(i - 127) * s1;
    float e = erff(y1 * 0.70710678118654752f);
    float y2 = (y1 * (e + 1.0f)) * 0.5f;
    float q2 = fminf(fmaxf(rintf(y2 / s2), -127.f), 127.f);
    tab[i] = q2 * s2;
  }
  const int img = blockIdx.x >> 2, ch = blockIdx.x & 3;   // 512 blocks: img x 4 q-chunks
  const int q0 = ch * 49;
  // stage k1[q0..q0+48][0..767] -> LDS, fully coalesced (2352 x uint4)
  const uint4* src = (const uint4*)(k1 + (size_t)img * 150528 + (size_t)q0 * 768);
  for (int i = t; i < 2352; i += 256) {
    uint4 v = src[i];
    const int q = i / 48, r = i - q * 48;
    *(uint4*)&ks[q * 772 + r * 16] = v;
  }
  __syncthreads();
  // write phase: wave per oc, lane per q (49 active) -> 196B contiguous runs
  const int lane = t & 63, wv = t >> 6;
  float* ob = out + (size_t)img * CHW + q0 + lane;
  if (lane < 49) {
    const signed char* kcol = &ks[lane * 772];
    for (int j = 0; j < 192; ++j) {
      const int oc = wv * 192 + j;
      const float iv = inv_[oc], sh = shf[oc];
      const int a = kcol[oc];
      const float f = __fadd_rn(__fmul_rn(tab[a + 127], iv), sh);
      ob[(size_t)oc * 196] = fminf(fmaxf(rintf(f / s3), -127.f), 127.f) * s3;
    }
  }
  if (blockIdx.x == 0 && t == 0) out[TOT] = s3;  // act_scale
}

extern "C" void kernel_launch(void* const* d_in, const int* in_sizes, int n_in,
                              void* d_out, int out_size, void* d_ws, size_t ws_size,
                              hipStream_t stream) {
  const float* x     = (const float*)d_in[0];
  const float* W     = (const float*)d_in[1];
  const float* bias  = (const float*)d_in[2];
  const float* gamma = (const float*)d_in[3];
  const float* beta  = (const float*)d_in[4];
  const float* rmean = (const float*)d_in[5];
  const float* rvar  = (const float*)d_in[6];
  float* out = (float*)d_out;
  char* ws = (char*)d_ws;

  signed char* aq  = (signed char*)(ws + OFF_AQ);
  signed char* wq  = (signed char*)(ws + OFF_WQ);
  float* wsc  = (float*)(ws + OFF_WSC);
  float* inv_ = (float*)(ws + OFF_INV);
  float* shf  = (float*)(ws + OFF_SHF);
  float* pA   = (float*)(ws + OFF_PA);
  float* pB   = (float*)(ws + OFF_PB);
  uint*  sc   = (uint*)(ws + OFF_SC);
  float* pmn  = (float*)(ws + OFF_PMN);
  float* pmx  = (float*)(ws + OFF_PMX);
  float* pm2  = (float*)(ws + OFF_PM2);   // overlays wq (dead after k_gemm)
  float* px2  = (float*)(ws + OFF_PX2);
  signed char* k1 = (signed char*)(ws + OFF_AQ);  // aliases aq (dead after GEMM)

  k_max_wq<<<1944, 256, 0, stream>>>(x, pA, W, gamma, beta, rmean, rvar, wq, wsc, inv_, shf);
  k_im2col<<<4704, 256, 0, stream>>>(x, pA, aq, sc);
  k_gemm<<<1176, 256, 0, stream>>>(aq, wq, bias, wsc, sc, out, pB);
  k_gelu<<<1568, 192, 0, stream>>>(out, pB, k1, pmn, pmx);
  k_chred<<<192, 256, 0, stream>>>(pmn, pmx, pm2, px2);
  k_scales<<<1, 256, 0, stream>>>(pB, pm2, px2, inv_, shf, sc);
  k_final<<<512, 256, 0, stream>>>(k1, sc, inv_, shf, out);
}

// Round 12
// 137.216 us; speedup vs baseline: 1.0225x; 1.0225x over previous
//
#include <hip/hip_runtime.h>

// Problem geometry
#define TOT   19267584   // 128*768*14*14 == 128*3*224*224
#define MROWS 25088      // 128*196 patches
#define KD    768        // 3*16*16
#define NPB   196
#define CHW   150528     // 768*196

typedef unsigned int uint;
typedef __attribute__((ext_vector_type(4))) int i32x4;

// workspace layout (bytes)
#define OFF_AQ   0ull              // i8 aq_t[196][12][128][64] = 19,267,584
#define OFF_WQ   19267584ull       // i8 wq_t[6][12][128][64] = 589,824
#define OFF_WSC  19857408ull       // float w_scale[768]
#define OFF_INV  19860480ull       // float inv[768]
#define OFF_SHF  19863552ull       // float shift[768]
#define OFF_PA   19866624ull       // float pA[1176]  (max|x| partials)
#define OFF_PB   19871328ull       // float pB[1176]  (max|y_conv| partials)
#define OFF_SC   19876032ull       // uint sc[4]: s1, s2, s3, ps bits
#define OFF_K1   19876864ull       // i8 k1[25088][768] = 19,267,584 (own region: aq live in pass B)
#define OFF_PMN  39144448ull       // float pmn[196][768] = 602,112
#define OFF_PMX  39746560ull       // float pmx[196][768] = 602,112
#define OFF_PM2  40348672ull       // float pm2[14][768] = 43,008
#define OFF_PX2  40391680ull       // float px2[14][768] = 43,008

__device__ __forceinline__ float wave_max(float v) {
#pragma unroll
  for (int off = 32; off > 0; off >>= 1) v = fmaxf(v, __shfl_xor(v, off));
  return v;
}

// block max for 256-thread blocks (4 waves); safe for repeated calls
__device__ __forceinline__ float block_max(float v) {
  __shared__ float red[4];
  v = wave_max(v);
  __syncthreads();
  if ((threadIdx.x & 63) == 0) red[threadIdx.x >> 6] = v;
  __syncthreads();
  return fmaxf(fmaxf(red[0], red[1]), fmaxf(red[2], red[3]));
}

// tiled i8 address: [blk128][ks][row128][64]
__device__ __forceinline__ size_t tiled_addr(int row, int k) {
  return (size_t)(row >> 7) * 98304 + (size_t)(k >> 6) * 8192 + ((row & 127) << 6) + (k & 63);
}

// ---------------- K0: fused max|x| partials (blocks 0..1175) + weight quant (1176..1943) ----
__global__ void k_max_wq(const float* __restrict__ x, float* __restrict__ pA,
                         const float* __restrict__ W, const float* __restrict__ gamma,
                         const float* __restrict__ beta, const float* __restrict__ rmean,
                         const float* __restrict__ rvar, signed char* __restrict__ wq,
                         float* __restrict__ wscale, float* __restrict__ inv_,
                         float* __restrict__ shf) {
  if (blockIdx.x < 1176) {
    const int i0 = blockIdx.x * 256 + threadIdx.x;   // 1176*256*16 = TOT/4 exact
    const float4* x4 = (const float4*)x;
    float m = 0.f;
#pragma unroll
    for (int j = 0; j < 16; j += 4) {
      float4 a = x4[i0 + (j + 0) * 301056];
      float4 b = x4[i0 + (j + 1) * 301056];
      float4 c = x4[i0 + (j + 2) * 301056];
      float4 d = x4[i0 + (j + 3) * 301056];
      m = fmaxf(m, fmaxf(fmaxf(fabsf(a.x), fabsf(a.y)), fmaxf(fabsf(a.z), fabsf(a.w))));
      m = fmaxf(m, fmaxf(fmaxf(fabsf(b.x), fabsf(b.y)), fmaxf(fabsf(b.z), fabsf(b.w))));
      m = fmaxf(m, fmaxf(fmaxf(fabsf(c.x), fabsf(c.y)), fmaxf(fabsf(c.z), fabsf(c.w))));
      m = fmaxf(m, fmaxf(fmaxf(fabsf(d.x), fabsf(d.y)), fmaxf(fabsf(d.z), fabsf(d.w))));
    }
    float bm = block_max(m);
    if (threadIdx.x == 0) pA[blockIdx.x] = bm;
  } else {
    const int oc = blockIdx.x - 1176;
    const float* row = W + oc * KD;
    float m = 0.f;
    for (int k = threadIdx.x; k < KD; k += 256) m = fmaxf(m, fabsf(row[k]));
    const float ws_ = block_max(m) / 127.0f;
    for (int k = threadIdx.x; k < KD; k += 256)
      wq[tiled_addr(oc, k)] = (signed char)(int)rintf(row[k] / ws_);
    if (threadIdx.x == 0) {
      wscale[oc] = ws_;
      float iv = gamma[oc] / sqrtf(rvar[oc] + 1e-5f);
      inv_[oc] = iv;
      shf[oc] = __fsub_rn(beta[oc], __fmul_rn(rmean[oc], iv));  // jax: mul then sub, no fma
    }
  }
}

// ---------------- K1: im2col + quant -> TILED aq; folds s0-combine; publishes ps ------------
__global__ void k_im2col(const float* __restrict__ x, const float* __restrict__ pA,
                         signed char* __restrict__ aq, uint* __restrict__ sc) {
  float mm = 0.f;
  for (int i = threadIdx.x; i < 1176; i += 256) mm = fmaxf(mm, pA[i]);
  const float ps = block_max(mm) / 127.0f;
  if (blockIdx.x == 0 && threadIdx.x == 0) sc[3] = __float_as_uint(ps);
  const int u = blockIdx.x * 256 + threadIdx.x;   // u < 1,204,224 = 25088*48 exact
  const int p = u / 48, r = u - p * 48;           // patch, (c,kh) row; k0 = r*16
  const int c = r >> 4, kh = r & 15;
  const int b = p / NPB, pp = p - b * NPB;
  const int ph = pp / 14, pw = pp - ph * 14;
  const float* src = x + (((b * 3 + c) * 224 + ph * 16 + kh) * 224 + pw * 16);
  float4 v0 = *(const float4*)(src);
  float4 v1 = *(const float4*)(src + 4);
  float4 v2 = *(const float4*)(src + 8);
  float4 v3 = *(const float4*)(src + 12);
#define Q8(v) ((int)fminf(fmaxf(rintf((v) / ps), -127.f), 127.f) & 255)
  uint4 o;
  o.x = Q8(v0.x) | (Q8(v0.y) << 8) | (Q8(v0.z) << 16) | ((uint)Q8(v0.w) << 24);
  o.y = Q8(v1.x) | (Q8(v1.y) << 8) | (Q8(v1.z) << 16) | ((uint)Q8(v1.w) << 24);
  o.z = Q8(v2.x) | (Q8(v2.y) << 8) | (Q8(v2.z) << 16) | ((uint)Q8(v2.w) << 24);
  o.w = Q8(v3.x) | (Q8(v3.y) << 8) | (Q8(v3.z) << 16) | ((uint)Q8(v3.w) << 24);
#undef Q8
  *(uint4*)(aq + (size_t)(p >> 7) * 98304 + (size_t)(r >> 2) * 8192 + ((p & 127) << 6) +
            ((r & 3) << 4)) = o;
}

// ---------------- shared GEMM pieces ---------------------------------------------------------
__device__ __forceinline__ void gl_lds16(const void* g, void* l) {
  __builtin_amdgcn_global_load_lds((const __attribute__((address_space(1))) void*)g,
                                   (__attribute__((address_space(3))) void*)l, 16, 0, 0);
}

// ---------------- K2a: GEMM pass A — max|y| only, NO y write --------------------------------
__global__ __launch_bounds__(256) void k_gemm_max(const signed char* __restrict__ aq,
                                                  const signed char* __restrict__ wq,
                                                  const float* __restrict__ bias,
                                                  const float* __restrict__ wscale,
                                                  const uint* __restrict__ sc,
                                                  float* __restrict__ pB) {
  __shared__ __align__(16) signed char lA[2][8192];
  __shared__ __align__(16) signed char lB[2][8192];
  const int tid = threadIdx.x, lane = tid & 63, wv = tid >> 6;
  const int bsw = (blockIdx.x & 7) * 147 + (blockIdx.x >> 3);
  const int bm = bsw / 6, bn = bsw - 6 * (bsw / 6);
  const int wr = wv >> 1, wc = wv & 1;

  const int ci0 = wv * 2, ci1 = wv * 2 + 1;
  const int lo = ((lane >> 2) << 6) + (((lane & 3) ^ ((lane >> 3) & 3)) << 4);
  const signed char* gA0 = aq + (size_t)bm * 98304 + ci0 * 1024 + lo;
  const signed char* gA1 = aq + (size_t)bm * 98304 + ci1 * 1024 + lo;
  const signed char* gB0 = wq + (size_t)bn * 98304 + ci0 * 1024 + lo;
  const signed char* gB1 = wq + (size_t)bn * 98304 + ci1 * 1024 + lo;

  i32x4 acc[4][4];
#pragma unroll
  for (int m = 0; m < 4; ++m)
#pragma unroll
    for (int n = 0; n < 4; ++n) acc[m][n] = (i32x4){0, 0, 0, 0};

  const int rbase = lane & 15;
  const int kg = ((lane >> 4) << 4) ^ (((lane >> 1) & 3) << 4);

#define STAGE(T, B)                                   \
  {                                                   \
    const size_t kk_ = (size_t)(T) * 8192;            \
    gl_lds16(gA0 + kk_, &lA[B][ci0 * 1024]);          \
    gl_lds16(gA1 + kk_, &lA[B][ci1 * 1024]);          \
    gl_lds16(gB0 + kk_, &lB[B][ci0 * 1024]);          \
    gl_lds16(gB1 + kk_, &lB[B][ci1 * 1024]);          \
  }
  STAGE(0, 0)
  __syncthreads();
  int cur = 0;
  for (int t = 0; t < 12; ++t) {
    if (t < 11) STAGE(t + 1, cur ^ 1)
    i32x4 af[4], bfr[4];
#pragma unroll
    for (int m = 0; m < 4; ++m)
      af[m] = *(const i32x4*)&lA[cur][(wr * 64 + m * 16 + rbase) * 64 + kg];
#pragma unroll
    for (int n = 0; n < 4; ++n)
      bfr[n] = *(const i32x4*)&lB[cur][(wc * 64 + n * 16 + rbase) * 64 + kg];
#pragma unroll
    for (int m = 0; m < 4; ++m)
#pragma unroll
      for (int n = 0; n < 4; ++n)
        acc[m][n] = __builtin_amdgcn_mfma_i32_16x16x64_i8(bfr[n], af[m], acc[m][n], 0, 0, 0);
    __syncthreads();
    cur ^= 1;
  }
#undef STAGE

  const float ps_ = __uint_as_float(sc[3]);
  float lmax = 0.f;
#pragma unroll
  for (int n = 0; n < 4; ++n) {
    const int ocb = bn * 128 + wc * 64 + n * 16 + ((lane >> 4) << 2);
    const float4 ws4 = *(const float4*)&wscale[ocb];
    const float4 b4 = *(const float4*)&bias[ocb];
    const float c0 = ws4.x * ps_, c1 = ws4.y * ps_, c2 = ws4.z * ps_, c3 = ws4.w * ps_;
    const float i0 = rintf(b4.x / c0), i1 = rintf(b4.y / c1);
    const float i2 = rintf(b4.z / c2), i3 = rintf(b4.w / c3);
#pragma unroll
    for (int m = 0; m < 4; ++m) {
      float ox = ((float)acc[m][n][0] + i0) * c0;
      float oy = ((float)acc[m][n][1] + i1) * c1;
      float oz = ((float)acc[m][n][2] + i2) * c2;
      float ow = ((float)acc[m][n][3] + i3) * c3;
      lmax = fmaxf(lmax, fmaxf(fmaxf(fabsf(ox), fabsf(oy)), fmaxf(fabsf(oz), fabsf(ow))));
    }
  }
  float bm_ = block_max(lmax);
  if (tid == 0) pB[blockIdx.x] = bm_;
}

// ---------------- K2b: GEMM pass B — recompute acc, quant to k1, gelu channel min/max -------
__global__ __launch_bounds__(256) void k_gemm_k1(const signed char* __restrict__ aq,
                                                 const signed char* __restrict__ wq,
                                                 const float* __restrict__ bias,
                                                 const float* __restrict__ wscale,
                                                 const uint* __restrict__ sc,
                                                 const float* __restrict__ pB,
                                                 signed char* __restrict__ k1,
                                                 float* __restrict__ pmn,
                                                 float* __restrict__ pmx) {
  __shared__ __align__(16) signed char lA[2][8192];
  __shared__ __align__(16) signed char lB[2][8192];
  __shared__ float tab[255];
  __shared__ float smnf[2][2][4][4][4], smxf[2][2][4][4][4];  // [wr][wc][n][g][j]
  const int tid = threadIdx.x, lane = tid & 63, wv = tid >> 6;
  const int bsw = (blockIdx.x & 7) * 147 + (blockIdx.x >> 3);
  const int bm = bsw / 6, bn = bsw - 6 * (bsw / 6);
  const int wr = wv >> 1, wc = wv & 1;

  // s1 combine + gelu LUT
  float mm = 0.f;
  for (int i = tid; i < 1176; i += 256) mm = fmaxf(mm, pB[i]);
  const float s1 = block_max(mm) / 127.0f;
  for (int i = tid; i < 255; i += 256) {
    float y1 = (float)(i - 127) * s1;
    float e = erff(y1 * 0.70710678118654752f);
    tab[i] = (y1 * (e + 1.0f)) * 0.5f;
  }

  const int ci0 = wv * 2, ci1 = wv * 2 + 1;
  const int lo = ((lane >> 2) << 6) + (((lane & 3) ^ ((lane >> 3) & 3)) << 4);
  const signed char* gA0 = aq + (size_t)bm * 98304 + ci0 * 1024 + lo;
  const signed char* gA1 = aq + (size_t)bm * 98304 + ci1 * 1024 + lo;
  const signed char* gB0 = wq + (size_t)bn * 98304 + ci0 * 1024 + lo;
  const signed char* gB1 = wq + (size_t)bn * 98304 + ci1 * 1024 + lo;

  i32x4 acc[4][4];
#pragma unroll
  for (int m = 0; m < 4; ++m)
#pragma unroll
    for (int n = 0; n < 4; ++n) acc[m][n] = (i32x4){0, 0, 0, 0};

  const int rbase = lane & 15;
  const int kg = ((lane >> 4) << 4) ^ (((lane >> 1) & 3) << 4);

#define STAGE(T, B)                                   \
  {                                                   \
    const size_t kk_ = (size_t)(T) * 8192;            \
    gl_lds16(gA0 + kk_, &lA[B][ci0 * 1024]);          \
    gl_lds16(gA1 + kk_, &lA[B][ci1 * 1024]);          \
    gl_lds16(gB0 + kk_, &lB[B][ci0 * 1024]);          \
    gl_lds16(gB1 + kk_, &lB[B][ci1 * 1024]);          \
  }
  STAGE(0, 0)
  __syncthreads();
  int cur = 0;
  for (int t = 0; t < 12; ++t) {
    if (t < 11) STAGE(t + 1, cur ^ 1)
    i32x4 af[4], bfr[4];
#pragma unroll
    for (int m = 0; m < 4; ++m)
      af[m] = *(const i32x4*)&lA[cur][(wr * 64 + m * 16 + rbase) * 64 + kg];
#pragma unroll
    for (int n = 0; n < 4; ++n)
      bfr[n] = *(const i32x4*)&lB[cur][(wc * 64 + n * 16 + rbase) * 64 + kg];
#pragma unroll
    for (int m = 0; m < 4; ++m)
#pragma unroll
      for (int n = 0; n < 4; ++n)
        acc[m][n] = __builtin_amdgcn_mfma_i32_16x16x64_i8(bfr[n], af[m], acc[m][n], 0, 0, 0);
    __syncthreads();
    cur ^= 1;
  }
#undef STAGE

  // epilogue: quantize to k1 (char4 stores, [p][oc]), gelu LUT, per-channel min/max
  const float ps_ = __uint_as_float(sc[3]);
  const int g = lane >> 4;
#pragma unroll
  for (int n = 0; n < 4; ++n) {
    const int ocb = bn * 128 + wc * 64 + n * 16 + (g << 2);
    const float4 ws4 = *(const float4*)&wscale[ocb];
    const float4 b4 = *(const float4*)&bias[ocb];
    const float c0 = ws4.x * ps_, c1 = ws4.y * ps_, c2 = ws4.z * ps_, c3 = ws4.w * ps_;
    const float i0 = rintf(b4.x / c0), i1 = rintf(b4.y / c1);
    const float i2 = rintf(b4.z / c2), i3 = rintf(b4.w / c3);
    float jmn0 = 1e30f, jmn1 = 1e30f, jmn2 = 1e30f, jmn3 = 1e30f;
    float jmx0 = -1e30f, jmx1 = -1e30f, jmx2 = -1e30f, jmx3 = -1e30f;
#pragma unroll
    for (int m = 0; m < 4; ++m) {
      const int p = bm * 128 + wr * 64 + m * 16 + rbase;
      float ox = ((float)acc[m][n][0] + i0) * c0;
      float oy = ((float)acc[m][n][1] + i1) * c1;
      float oz = ((float)acc[m][n][2] + i2) * c2;
      float ow = ((float)acc[m][n][3] + i3) * c3;
      int q0 = (int)fminf(fmaxf(rintf(ox / s1), -127.f), 127.f);
      int q1 = (int)fminf(fmaxf(rintf(oy / s1), -127.f), 127.f);
      int q2 = (int)fminf(fmaxf(rintf(oz / s1), -127.f), 127.f);
      int q3 = (int)fminf(fmaxf(rintf(ow / s1), -127.f), 127.f);
      char4 kk;
      kk.x = (signed char)q0; kk.y = (signed char)q1;
      kk.z = (signed char)q2; kk.w = (signed char)q3;
      *(char4*)(k1 + (size_t)p * 768 + ocb) = kk;
      float g0 = tab[q0 + 127], g1 = tab[q1 + 127], g2 = tab[q2 + 127], g3 = tab[q3 + 127];
      jmn0 = fminf(jmn0, g0); jmx0 = fmaxf(jmx0, g0);
      jmn1 = fminf(jmn1, g1); jmx1 = fmaxf(jmx1, g1);
      jmn2 = fminf(jmn2, g2); jmx2 = fmaxf(jmx2, g2);
      jmn3 = fminf(jmn3, g3); jmx3 = fmaxf(jmx3, g3);
    }
    // reduce over the 16 lanes of this g-group (same 4 channels, different p)
#pragma unroll
    for (int off = 1; off < 16; off <<= 1) {
      jmn0 = fminf(jmn0, __shfl_xor(jmn0, off)); jmx0 = fmaxf(jmx0, __shfl_xor(jmx0, off));
      jmn1 = fminf(jmn1, __shfl_xor(jmn1, off)); jmx1 = fmaxf(jmx1, __shfl_xor(jmx1, off));
      jmn2 = fminf(jmn2, __shfl_xor(jmn2, off)); jmx2 = fmaxf(jmx2, __shfl_xor(jmx2, off));
      jmn3 = fminf(jmn3, __shfl_xor(jmn3, off)); jmx3 = fmaxf(jmx3, __shfl_xor(jmx3, off));
    }
    if (rbase == 0) {
      smnf[wr][wc][n][g][0] = jmn0; smnf[wr][wc][n][g][1] = jmn1;
      smnf[wr][wc][n][g][2] = jmn2; smnf[wr][wc][n][g][3] = jmn3;
      smxf[wr][wc][n][g][0] = jmx0; smxf[wr][wc][n][g][1] = jmx1;
      smxf[wr][wc][n][g][2] = jmx2; smxf[wr][wc][n][g][3] = jmx3;
    }
  }
  __syncthreads();
  if (tid < 128) {
    const int wcc = tid >> 6, r = tid & 63;
    const int nn = r >> 4, gg = (r >> 2) & 3, jj = tid & 3;
    float mn = fminf(smnf[0][wcc][nn][gg][jj], smnf[1][wcc][nn][gg][jj]);
    float mx = fmaxf(smxf[0][wcc][nn][gg][jj], smxf[1][wcc][nn][gg][jj]);
    pmn[(size_t)bm * 768 + bn * 128 + tid] = mn;
    pmx[(size_t)bm * 768 + bn * 128 + tid] = mx;
  }
}

// ---------------- K4: stage-1 channel reduce: 168 blocks (12 cg x 14 row-chunks) ------------
__global__ void k_chred(const float* __restrict__ pmn, const float* __restrict__ pmx,
                        float* __restrict__ pm2, float* __restrict__ px2) {
  const int cg = blockIdx.x % 12, rc = blockIdx.x / 12;   // rc < 14
  const int lane = threadIdx.x & 63, wv = threadIdx.x >> 6;
  const int c = cg * 64 + lane;
  float lo = 1e30f, hi = -1e30f;
  for (int i = wv; i < 14; i += 4) {
    const size_t a = (size_t)(rc * 14 + i) * 768 + c;   // 64 lanes = 256B coalesced
    lo = fminf(lo, pmn[a]);
    hi = fmaxf(hi, pmx[a]);
  }
  __shared__ float smn[4][64], smx[4][64];
  smn[wv][lane] = lo;
  smx[wv][lane] = hi;
  __syncthreads();
  if (threadIdx.x < 64) {
    float l = fminf(fminf(smn[0][lane], smn[1][lane]), fminf(smn[2][lane], smn[3][lane]));
    float h = fmaxf(fmaxf(smx[0][lane], smx[1][lane]), fmaxf(smx[2][lane], smx[3][lane]));
    pm2[rc * 768 + c] = l;
    px2[rc * 768 + c] = h;
  }
}

// ---------------- K5: scalars s1, s2, s3 (folds stage-2 channel reduce) --------------------
__global__ void k_scales(const float* __restrict__ pB, const float* __restrict__ pm2,
                         const float* __restrict__ px2, const float* __restrict__ inv_,
                         const float* __restrict__ shf, uint* __restrict__ sc) {
  const int t = threadIdx.x;
  float m = 0.f;
  for (int i = t; i < 1176; i += 256) m = fmaxf(m, pB[i]);
  const float s1 = block_max(m) / 127.0f;
  float cmn[3], cmx[3];
  float m2 = 0.f;
#pragma unroll
  for (int ci = 0; ci < 3; ++ci) {
    const int c = t + ci * 256;
    float mn = 1e30f, mx = -1e30f;
#pragma unroll
    for (int r = 0; r < 14; ++r) {
      mn = fminf(mn, pm2[r * 768 + c]);
      mx = fmaxf(mx, px2[r * 768 + c]);
    }
    cmn[ci] = mn;
    cmx[ci] = mx;
    m2 = fmaxf(m2, fmaxf(fabsf(mn), fabsf(mx)));
  }
  const float s2 = block_max(m2) / 127.0f;
  float m4 = 0.f;
#pragma unroll
  for (int ci = 0; ci < 3; ++ci) {
    const int c = t + ci * 256;
    float iv = inv_[c], sh = shf[c];
    float a = fminf(fmaxf(rintf(cmn[ci] / s2), -127.f), 127.f) * s2;
    float b = fminf(fmaxf(rintf(cmx[ci] / s2), -127.f), 127.f) * s2;
    float ya = __fadd_rn(__fmul_rn(a, iv), sh);
    float yb = __fadd_rn(__fmul_rn(b, iv), sh);
    m4 = fmaxf(m4, fmaxf(fabsf(ya), fabsf(yb)));
  }
  const float s3 = block_max(m4) / 127.0f;
  if (t == 0) {
    sc[0] = __float_as_uint(s1);
    sc[1] = __float_as_uint(s2);
    sc[2] = __float_as_uint(s3);
  }
}

// ---------------- K6: final via LDS transpose: coalesced k1 reads, 196B output runs --------
__global__ __launch_bounds__(256) void k_final(const signed char* __restrict__ k1,
                                               const uint* __restrict__ sc,
                                               const float* __restrict__ inv_,
                                               const float* __restrict__ shf,
                                               float* __restrict__ out) {
  __shared__ signed char ks[49 * 772];   // [q][772] padded (bank-spread for column reads)
  __shared__ float tab[255];
  const float s1 = __uint_as_float(sc[0]);
  const float s2 = __uint_as_float(sc[1]);
  const float s3 = __uint_as_float(sc[2]);
  const int t = threadIdx.x;
  for (int i = t; i < 255; i += 256) {
    float y1 = (float)(i - 127) * s1;
    float e = erff(y1 * 0.70710678118654752f);
    float y2 = (y1 * (e + 1.0f)) * 0.5f;
    float q2 = fminf(fmaxf(rintf(y2 / s2), -127.f), 127.f);
    tab[i] = q2 * s2;
  }
  const int img = blockIdx.x >> 2, ch = blockIdx.x & 3;   // 512 blocks: img x 4 q-chunks
  const int q0 = ch * 49;
  const uint4* src = (const uint4*)(k1 + (size_t)img * 150528 + (size_t)q0 * 768);
  for (int i = t; i < 2352; i += 256) {
    uint4 v = src[i];
    const int q = i / 48, r = i - q * 48;
    *(uint4*)&ks[q * 772 + r * 16] = v;
  }
  __syncthreads();
  const int lane = t & 63, wv = t >> 6;
  float* ob = out + (size_t)img * CHW + q0 + lane;
  if (lane < 49) {
    const signed char* kcol = &ks[lane * 772];
    for (int j = 0; j < 192; ++j) {
      const int oc = wv * 192 + j;
      const float iv = inv_[oc], sh = shf[oc];
      const int a = kcol[oc];
      const float f = __fadd_rn(__fmul_rn(tab[a + 127], iv), sh);
      ob[(size_t)oc * 196] = fminf(fmaxf(rintf(f / s3), -127.f), 127.f) * s3;
    }
  }
  if (blockIdx.x == 0 && t == 0) out[TOT] = s3;  // act_scale
}

extern "C" void kernel_launch(void* const* d_in, const int* in_sizes, int n_in,
                              void* d_out, int out_size, void* d_ws, size_t ws_size,
                              hipStream_t stream) {
  const float* x     = (const float*)d_in[0];
  const float* W     = (const float*)d_in[1];
  const float* bias  = (const float*)d_in[2];
  const float* gamma = (const float*)d_in[3];
  const float* beta  = (const float*)d_in[4];
  const float* rmean = (const float*)d_in[5];
  const float* rvar  = (const float*)d_in[6];
  float* out = (float*)d_out;
  char* ws = (char*)d_ws;

  signed char* aq  = (signed char*)(ws + OFF_AQ);
  signed char* wq  = (signed char*)(ws + OFF_WQ);
  float* wsc  = (float*)(ws + OFF_WSC);
  float* inv_ = (float*)(ws + OFF_INV);
  float* shf  = (float*)(ws + OFF_SHF);
  float* pA   = (float*)(ws + OFF_PA);
  float* pB   = (float*)(ws + OFF_PB);
  uint*  sc   = (uint*)(ws + OFF_SC);
  signed char* k1 = (signed char*)(ws + OFF_K1);
  float* pmn  = (float*)(ws + OFF_PMN);
  float* pmx  = (float*)(ws + OFF_PMX);
  float* pm2  = (float*)(ws + OFF_PM2);
  float* px2  = (float*)(ws + OFF_PX2);

  k_max_wq<<<1944, 256, 0, stream>>>(x, pA, W, gamma, beta, rmean, rvar, wq, wsc, inv_, shf);
  k_im2col<<<4704, 256, 0, stream>>>(x, pA, aq, sc);
  k_gemm_max<<<1176, 256, 0, stream>>>(aq, wq, bias, wsc, sc, pB);
  k_gemm_k1<<<1176, 256, 0, stream>>>(aq, wq, bias, wsc, sc, pB, k1, pmn, pmx);
  k_chred<<<168, 256, 0, stream>>>(pmn, pmx, pm2, px2);
  k_scales<<<1, 256, 0, stream>>>(pB, pm2, px2, inv_, shf, sc);
  k_final<<<512, 256, 0, stream>>>(k1, sc, inv_, shf, out);
}